// Round 2
// baseline (21.038 us; speedup 1.0000x reference)
//
#include <hip/hip_runtime.h>

typedef float float4v __attribute__((ext_vector_type(4)));

// out[token*768 + d] = emb[x[token]*768 + d] * scale(d)
// scale(d) = w3 + (d<576)*w2 + (d<384)*w1 + (d<192)*w0
// One float4 per thread, full grid (no loop). Non-temporal store: output is
// write-once, keep L2/L3 for the gathered embedding table instead.
__global__ void mixed_embed_kernel(const int* __restrict__ x,
                                   const float* __restrict__ w,
                                   const float* __restrict__ emb,
                                   float* __restrict__ out,
                                   int n_vec) {
    const int gid = blockIdx.x * blockDim.x + threadIdx.x;
    if (gid >= n_vec) return;

    const float w0 = w[0], w1 = w[1], w2 = w[2], w3 = w[3];

    const int token = gid / 192;          // magic-multiply, cheap
    const int d4    = gid - token * 192;  // float4 column index [0,192)
    const int row   = x[token];           // 192 consecutive lanes share this -> cached

    const float4v v = reinterpret_cast<const float4v*>(emb)[(long)row * 192 + d4];

    // Branchless piecewise-constant scale (no runtime-indexed array -> no scratch).
    float s = w3;
    s += (d4 < 144) ? w2 : 0.0f;   // d < 576
    s += (d4 <  96) ? w1 : 0.0f;   // d < 384
    s += (d4 <  48) ? w0 : 0.0f;   // d < 192

    float4v o = v;
    o[0] *= s; o[1] *= s; o[2] *= s; o[3] *= s;
    __builtin_nontemporal_store(o, reinterpret_cast<float4v*>(out) + gid);
}

extern "C" void kernel_launch(void* const* d_in, const int* in_sizes, int n_in,
                              void* d_out, int out_size, void* d_ws, size_t ws_size,
                              hipStream_t stream) {
    const int*   x   = (const int*)d_in[0];    // [8*2048] token ids
    const float* w   = (const float*)d_in[1];  // [4] mixture weights
    const float* emb = (const float*)d_in[2];  // [50257*768]
    float*       out = (float*)d_out;          // [8*2048*768]

    const int n_vec = out_size / 4;            // float4 count = 3,145,728
    const int block = 256;
    const int grid  = (n_vec + block - 1) / block;  // 12288 blocks, full coverage

    mixed_embed_kernel<<<grid, block, 0, stream>>>(x, w, emb, out, n_vec);
}

// Round 3
// 20.314 us; speedup vs baseline: 1.0356x; 1.0356x over previous
//
#include <hip/hip_runtime.h>

typedef float float4v __attribute__((ext_vector_type(4)));

// One wave (64 lanes) per token. Each token = 192 float4s = 3 per lane.
// token is wave-uniform -> readfirstlane forces the x[] load onto the scalar
// path (1 s_load per wave instead of 64 vector loads). The 3 gathers are
// independent -> 3-deep memory-level parallelism per wave.
// scale(d) = w3 + (d<576)*w2 + (d<384)*w1 + (d<192)*w0, d = 4*d4+j.
__global__ void __launch_bounds__(256) mixed_embed_kernel(
    const int* __restrict__ x,
    const float* __restrict__ w,
    const float* __restrict__ emb,
    float* __restrict__ out) {
    const int lane = threadIdx.x & 63;
    const int wave = threadIdx.x >> 6;

    int token = blockIdx.x * 4 + wave;                 // wave-uniform
    token = __builtin_amdgcn_readfirstlane(token);     // force SGPR
    const int row = x[token];                          // scalar load

    const float w0 = w[0], w1 = w[1], w2 = w[2], w3 = w[3];

    const float4v* __restrict__ src =
        reinterpret_cast<const float4v*>(emb) + (long)row * 192;
    float4v* __restrict__ dst =
        reinterpret_cast<float4v*>(out) + (long)token * 192;

    // Three independent 16B loads (compiler issues back-to-back).
    float4v v0 = src[lane];
    float4v v1 = src[lane + 64];
    float4v v2 = src[lane + 128];

    // Per-segment scales: d4 = lane + 64k; thresholds 48/96/144.
    const float s0 = w3 + w2 + w1 + ((lane < 48) ? w0 : 0.0f);  // d4 in [0,64)
    const float s1 = w3 + w2 +      ((lane < 32) ? w1 : 0.0f);  // d4 in [64,128)
    const float s2 = w3 +           ((lane < 16) ? w2 : 0.0f);  // d4 in [128,192)

    float4v o0 = v0; o0[0] *= s0; o0[1] *= s0; o0[2] *= s0; o0[3] *= s0;
    float4v o1 = v1; o1[0] *= s1; o1[1] *= s1; o1[2] *= s1; o1[3] *= s1;
    float4v o2 = v2; o2[0] *= s2; o2[1] *= s2; o2[2] *= s2; o2[3] *= s2;

    __builtin_nontemporal_store(o0, dst + lane);
    __builtin_nontemporal_store(o1, dst + lane + 64);
    __builtin_nontemporal_store(o2, dst + lane + 128);
}

extern "C" void kernel_launch(void* const* d_in, const int* in_sizes, int n_in,
                              void* d_out, int out_size, void* d_ws, size_t ws_size,
                              hipStream_t stream) {
    const int*   x   = (const int*)d_in[0];    // [8*2048] token ids
    const float* w   = (const float*)d_in[1];  // [4] mixture weights
    const float* emb = (const float*)d_in[2];  // [50257*768]
    float*       out = (float*)d_out;          // [8*2048*768]

    const int n_tokens = out_size / 768;       // 16384
    const int grid = n_tokens / 4;             // 4 tokens per 256-thread block

    mixed_embed_kernel<<<grid, 256, 0, stream>>>(x, w, emb, out);
}